// Round 1
// baseline (1319.125 us; speedup 1.0000x reference)
//
#include <hip/hip_runtime.h>
#include <hip/hip_fp16.h>

#define TT 800
#define CC 80
#define BB 16
#define SS 128
#define INFV 1e9f

// Bool masks may arrive as 1-byte numpy bools or int32 — detected at runtime.
__device__ inline bool mask_get(const void* p, int idx, int isInt) {
  if (isInt) return ((const int*)p)[idx] != 0;
  return ((const unsigned char*)p)[idx] != 0;
}

// Single block: detect mask element width, compute d_loss into out[2].
__global__ __launch_bounds__(256) void detect_dloss_kernel(
    const float* __restrict__ d, const int* __restrict__ mel_len,
    const void* __restrict__ src_mask, const void* __restrict__ pred_mask,
    int* __restrict__ flags, float* __restrict__ out)
{
  __shared__ int nzs, nzp;
  __shared__ float lb[BB];
  int tid = threadIdx.x;
  if (tid == 0) { nzs = 0; nzp = 0; }
  __syncthreads();
  const unsigned char* sm = (const unsigned char*)src_mask;
  const unsigned char* pm = (const unsigned char*)pred_mask;
  int f = 0;
  for (int i = tid; i < BB * SS; i += 256) if ((i & 3) && sm[i]) f = 1;
  if (f) atomicOr(&nzs, 1);
  f = 0;
  for (int i = tid; i < BB * TT; i += 256) if ((i & 3) && pm[i]) f = 1;
  if (f) atomicOr(&nzp, 1);
  __syncthreads();
  int isIntS = nzs ? 0 : 1;   // nonzero byte off int-boundary => 1-byte bools
  if (tid == 0) { flags[0] = isIntS; flags[1] = nzp ? 0 : 1; }

  // d_loss: 16 lanes-of-16 per batch row
  int b = tid >> 4, k = tid & 15;
  float sd = 0.f, so = 0.f;
  for (int s = k; s < SS; s += 16) {
    bool m = mask_get(src_mask, b * SS + s, isIntS);
    if (!m) { sd += d[b * SS + s]; so += 1.f; }
  }
  for (int off = 8; off; off >>= 1) {
    sd += __shfl_down(sd, off, 16);
    so += __shfl_down(so, off, 16);
  }
  if (k == 0) lb[b] = fabsf((float)mel_len[b] - sd) / so;
  __syncthreads();
  if (tid == 0) {
    float s = 0.f;
    for (int i = 0; i < BB; i++) s += lb[i];
    out[2] = s / (float)BB;
  }
}

// Tiled squared-distance cost matrix with fused mask+sigmoid.
// D[slot][i][j] = sum_c (sig(x[i,c]) - sig(y[j,c]))^2, stored fp16.
__global__ __launch_bounds__(256) void cost_kernel(
    const float* __restrict__ mel, const float* __restrict__ post,
    const float* __restrict__ target, const void* __restrict__ pred_mask,
    const int* __restrict__ flags, __half* __restrict__ D, int probBase)
{
  int slot = blockIdx.z;
  int prob = probBase + slot;
  int which = prob >> 4, b = prob & 15;
  const float* X = (which ? post : mel) + (size_t)b * TT * CC;
  const float* Y = target + (size_t)b * TT * CC;
  __half* Dp = D + (size_t)slot * TT * TT;
  int i0 = blockIdx.y * 64, j0 = blockIdx.x * 64;
  int isInt = flags[1];

  __shared__ __attribute__((aligned(16))) float As[16][68];
  __shared__ __attribute__((aligned(16))) float Bs[16][68];

  int tid = threadIdx.x;
  int kk = tid & 15, r4 = tid >> 4;   // staging: k-slot, row-group
  int tx = tid & 15, ty = tid >> 4;   // compute: 4-col group, 4-row group
  float acc[4][4] = {};

  for (int kc = 0; kc < CC; kc += 16) {
    __syncthreads();
#pragma unroll
    for (int q = 0; q < 4; q++) {
      int i = r4 + q * 16;
      int gia = i0 + i, gib = j0 + i;
      float xs = 0.f, ys = 0.f;
      if (gia < TT) {
        float v = X[(size_t)gia * CC + kc + kk];
        if (which == 0 && mask_get(pred_mask, b * TT + gia, isInt)) v = 0.f;
        xs = 1.f / (1.f + __expf(-v));
      }
      if (gib < TT) {
        float w = Y[(size_t)gib * CC + kc + kk];
        ys = 1.f / (1.f + __expf(-w));
      }
      As[kk][i] = xs;
      Bs[kk][i] = ys;
    }
    __syncthreads();
#pragma unroll
    for (int k = 0; k < 16; k++) {
      float4 a4 = *(const float4*)&As[k][ty * 4];
      float4 b4 = *(const float4*)&Bs[k][tx * 4];
      float am[4] = {a4.x, a4.y, a4.z, a4.w};
      float bn[4] = {b4.x, b4.y, b4.z, b4.w};
#pragma unroll
      for (int m = 0; m < 4; m++)
#pragma unroll
        for (int n = 0; n < 4; n++) {
          float df = am[m] - bn[n];
          acc[m][n] = fmaf(df, df, acc[m][n]);
        }
    }
  }

  int jc = j0 + tx * 4;
  if (jc < TT) {
#pragma unroll
    for (int m = 0; m < 4; m++) {
      int ic = i0 + ty * 4 + m;
      if (ic < TT) {
        union { __half h[4]; uint2 u; } cv;
#pragma unroll
        for (int n = 0; n < 4; n++) cv.h[n] = __float2half(acc[m][n]);
        *(uint2*)&Dp[(size_t)ic * TT + jc] = cv.u;
      }
    }
  }
}

// Anti-diagonal soft-DTW recursion. One block per (which,b) problem.
// Replicates reference semantics: INF=1e9 for invalid cells, corner only at p==0.
__global__ __launch_bounds__(832) void dtw_kernel(
    const __half* __restrict__ D, float* __restrict__ out, int probBase)
{
  __shared__ float buf[3][TT];
  int tid = threadIdx.x;
  int slot = blockIdx.x;
  int prob = probBase + slot;
  int which = prob >> 4;
  const __half* Dp = D + (size_t)slot * TT * TT;

  if (tid < TT) { buf[1][tid] = INFV; buf[2][tid] = INFV; }
  __syncthreads();

  const float g = 0.1f, invg = 10.0f;
  for (int p = 0; p < 2 * TT - 1; p++) {
    float* rw = buf[p % 3];
    const float* r1 = buf[(p + 2) % 3];
    const float* r2 = buf[(p + 1) % 3];
    if (tid < TT) {
      int i = tid, j = p - i;
      float r;
      if (j >= 0 && j < TT) {
        float dd = __half2float(Dp[(size_t)i * TT + j]);
        float up   = (i > 0) ? r1[i - 1] : INFV;
        float left = r1[i];
        float diag = (i > 0) ? r2[i - 1] : ((p == 0) ? 0.0f : INFV);
        float m = fminf(up, fminf(left, diag));
        float s = __expf((m - up) * invg) + __expf((m - left) * invg) +
                  __expf((m - diag) * invg);
        r = dd + m - g * __logf(s);
      } else {
        r = INFV;
      }
      rw[i] = r;
      if (p == 2 * TT - 2 && i == TT - 1)
        atomicAdd(&out[which], r * (0.001f / (float)BB));
    }
    __syncthreads();
  }
}

extern "C" void kernel_launch(void* const* d_in, const int* in_sizes, int n_in,
                              void* d_out, int out_size, void* d_ws, size_t ws_size,
                              hipStream_t stream) {
  const float* d        = (const float*)d_in[0];
  const int*   mel_len  = (const int*)d_in[1];
  const float* mel      = (const float*)d_in[2];
  const float* post     = (const float*)d_in[3];
  const float* target   = (const float*)d_in[4];
  const void*  src_mask = d_in[5];
  const void*  pred_mask= d_in[6];
  float* out = (float*)d_out;

  int* flags = (int*)d_ws;
  __half* D = (__half*)((char*)d_ws + 256);
  size_t per = (size_t)TT * TT * sizeof(__half);  // 1.28 MB per problem
  int slots = 0;
  if (ws_size > 256) slots = (int)((ws_size - 256) / per);
  if (slots > 32) slots = 32;

  hipMemsetAsync(d_out, 0, 3 * sizeof(float), stream);
  detect_dloss_kernel<<<1, 256, 0, stream>>>(d, mel_len, src_mask, pred_mask, flags, out);
  if (slots < 1) return;  // ws too small — learn ws_size from the failure

  for (int base = 0; base < 32; base += slots) {
    int g = (32 - base < slots) ? (32 - base) : slots;
    cost_kernel<<<dim3(13, 13, g), 256, 0, stream>>>(mel, post, target, pred_mask,
                                                     flags, D, base);
    dtw_kernel<<<g, 832, 0, stream>>>(D, out, base);
  }
}

// Round 3
// 640.800 us; speedup vs baseline: 2.0586x; 2.0586x over previous
//
#include <hip/hip_runtime.h>
#include <hip/hip_fp16.h>

#define TT 800
#define CC 80
#define BB 16
#define SS 128
#define INFV 1e9f
#define UPAD 864          // padded diagonal steps per band (valid u: 0..862)
#define KSTEP 32          // steps per chunk
#define NLC 27            // local chunks per band (ceil(863/32))
#define LAG 3             // chunk skew between bands (guarantees 63-step lag)
#define NGC 35            // global chunks: band3 needs lc<=25 -> G<=34

// Bool masks may arrive as 1-byte numpy bools or int32 — detected at runtime.
__device__ inline bool mask_get(const void* p, int idx, int isInt) {
  if (isInt) return ((const int*)p)[idx] != 0;
  return ((const unsigned char*)p)[idx] != 0;
}

// Single block: detect mask element width, compute d_loss into out[2].
__global__ __launch_bounds__(256) void detect_dloss_kernel(
    const float* __restrict__ d, const int* __restrict__ mel_len,
    const void* __restrict__ src_mask, const void* __restrict__ pred_mask,
    int* __restrict__ flags, float* __restrict__ out)
{
  __shared__ int nzs, nzp;
  __shared__ float lb[BB];
  int tid = threadIdx.x;
  if (tid == 0) { nzs = 0; nzp = 0; }
  __syncthreads();
  const unsigned char* sm = (const unsigned char*)src_mask;
  const unsigned char* pm = (const unsigned char*)pred_mask;
  int f = 0;
  for (int i = tid; i < BB * SS; i += 256) if ((i & 3) && sm[i]) f = 1;
  if (f) atomicOr(&nzs, 1);
  f = 0;
  for (int i = tid; i < BB * TT; i += 256) if ((i & 3) && pm[i]) f = 1;
  if (f) atomicOr(&nzp, 1);
  __syncthreads();
  int isIntS = nzs ? 0 : 1;
  if (tid == 0) { flags[0] = isIntS; flags[1] = nzp ? 0 : 1; }

  int b = tid >> 4, k = tid & 15;
  float sd = 0.f, so = 0.f;
  for (int s = k; s < SS; s += 16) {
    bool m = mask_get(src_mask, b * SS + s, isIntS);
    if (!m) { sd += d[b * SS + s]; so += 1.f; }
  }
  for (int off = 8; off; off >>= 1) {
    sd += __shfl_down(sd, off, 16);
    so += __shfl_down(so, off, 16);
  }
  if (k == 0) lb[b] = fabsf((float)mel_len[b] - sd) / so;
  __syncthreads();
  if (tid == 0) {
    float s = 0.f;
    for (int i = 0; i < BB; i++) s += lb[i];
    out[2] = s / (float)BB;
  }
}

// Cost matrix in diagonal-skewed layout:
//   Dsk[slot][band][u][l][rr] (halfs), element = D[256*band + 4*l + rr][u - l]
__global__ __launch_bounds__(256) void cost_kernel(
    const float* __restrict__ mel, const float* __restrict__ post,
    const float* __restrict__ target, const void* __restrict__ pred_mask,
    const int* __restrict__ flags, __half* __restrict__ Dsk, int probBase)
{
  int slot = blockIdx.z;
  int prob = probBase + slot;
  int which = prob >> 4, b = prob & 15;
  const float* X = (which ? post : mel) + (size_t)b * TT * CC;
  const float* Y = target + (size_t)b * TT * CC;
  int i0 = blockIdx.y * 64, j0 = blockIdx.x * 64;
  int isInt = flags[1];

  __shared__ __attribute__((aligned(16))) float As[16][68];
  __shared__ __attribute__((aligned(16))) float Bs[16][68];
  __shared__ __half S[79][70];   // [u_rel][i_local] skew-restage buffer

  int tid = threadIdx.x;
  int kk = tid & 15, r4 = tid >> 4;   // staging roles
  int tx = tid & 15, ty = tid >> 4;   // compute roles
  float acc[4][4] = {};

  for (int kc = 0; kc < CC; kc += 16) {
    __syncthreads();
#pragma unroll
    for (int q = 0; q < 4; q++) {
      int i = r4 + q * 16;
      int gia = i0 + i, gib = j0 + i;
      float xs = 0.f, ys = 0.f;
      if (gia < TT) {
        float v = X[(size_t)gia * CC + kc + kk];
        if (which == 0 && mask_get(pred_mask, b * TT + gia, isInt)) v = 0.f;
        xs = 1.f / (1.f + __expf(-v));
      }
      if (gib < TT) {
        float wv = Y[(size_t)gib * CC + kc + kk];
        ys = 1.f / (1.f + __expf(-wv));
      }
      As[kk][i] = xs;
      Bs[kk][i] = ys;
    }
    __syncthreads();
#pragma unroll
    for (int k = 0; k < 16; k++) {
      float4 a4 = *(const float4*)&As[k][ty * 4];
      float4 b4 = *(const float4*)&Bs[k][tx * 4];
      float am[4] = {a4.x, a4.y, a4.z, a4.w};
      float bn[4] = {b4.x, b4.y, b4.z, b4.w};
#pragma unroll
      for (int m = 0; m < 4; m++)
#pragma unroll
        for (int n = 0; n < 4; n++) {
          float df = am[m] - bn[n];
          acc[m][n] = fmaf(df, df, acc[m][n]);
        }
    }
  }

  __syncthreads();
#pragma unroll
  for (int m = 0; m < 4; m++)
#pragma unroll
    for (int n = 0; n < 4; n++)
      S[tx * 4 + n + ty][ty * 4 + m] = __float2half(acc[m][n]);
  __syncthreads();

  int lane = tid & 63, grp = tid >> 6;
  int band = i0 >> 8;
  int l_base4 = i0 & 255;
  int l_off = lane >> 2;
  size_t urow0 = ((size_t)slot * 4 + band) * UPAD + (size_t)(j0 + (l_base4 >> 2));
  for (int ur = grp; ur < 79; ur += 4) {
    int jrel = ur - l_off;
    int jj = j0 + jrel;
    int ii = i0 + lane;
    if (jrel >= 0 && jrel < 64 && jj < TT && ii < TT)
      Dsk[(urow0 + ur) * 256 + l_base4 + lane] = S[ur][lane];
  }
}

__device__ __forceinline__ float softmin_cell(float d, float up, float left, float diag) {
  float m = fminf(fminf(up, left), diag);
  float s = __expf((m - up) * 10.0f) + __expf((m - left) * 10.0f) +
            __expf((m - diag) * 10.0f);
  return d + m - 0.1f * __logf(s);
}

// Wave-pipelined soft-DTW: 4 waves = 4 row-bands of 256 (lane owns 4 rows).
// Cross-lane dep via one shfl_up/step; cross-wave via LDS ring + per-chunk barrier.
// D reads go straight to registers (512B/wave/step, coalesced), double-buffered
// in groups of 8 steps.
__global__ __launch_bounds__(256) void dtw_kernel(
    const __half* __restrict__ Dsk, float* __restrict__ out, int probBase)
{
  __shared__ float bnd[3][128];               // band-boundary rings
  const int tid = threadIdx.x;
  const int w = tid >> 6, lane = tid & 63;
  const int slot = blockIdx.x;
  const int prob = probBase + slot;
  const int which = prob >> 4;
  const __half* Db = Dsk + ((size_t)slot * 4 + w) * (size_t)(UPAD * 256) + lane * 4;

  const bool rowok = (256 * w + 4 * lane + 3) < TT;
  float cur0 = INFV, cur1 = INFV, cur2 = INFV, cur3 = INFV;
  float up0_prev = INFV, bnd_prev = INFV;

  uint2 bufA[8], bufB[8];

#define LOADG(BUF, UB) do {                                              \
    _Pragma("unroll")                                                    \
    for (int t = 0; t < 8; ++t) {                                        \
      int uu = (UB) + t; if (uu >= UPAD) uu = UPAD - 1;                  \
      BUF[t] = *(const uint2*)(Db + (size_t)uu * 256);                   \
    } } while (0)

#define STEP8(BUF, UB) do {                                              \
    _Pragma("unroll")                                                    \
    for (int k = 0; k < 8; ++k) {                                        \
      int u = (UB) + k;                                                  \
      float up0v = __shfl_up(cur3, 1, 64);                               \
      float diag0v = up0_prev;                                           \
      up0_prev = up0v;                                                   \
      if (w == 0) {                                                      \
        if (lane == 0) { up0v = INFV; diag0v = (u == 0) ? 0.0f : INFV; } \
      } else {                                                           \
        float bv = bnd[w - 1][u & 127];                                  \
        if (lane == 0) { up0v = bv; diag0v = bnd_prev; }                 \
        bnd_prev = bv;                                                   \
      }                                                                  \
      union { uint2 u2; __half h[4]; } cv; cv.u2 = BUF[k];               \
      float d0 = __half2float(cv.h[0]), d1 = __half2float(cv.h[1]);      \
      float d2 = __half2float(cv.h[2]), d3 = __half2float(cv.h[3]);      \
      float oc0 = cur0, oc1 = cur1, oc2 = cur2;                          \
      int j = u - lane;                                                  \
      bool act = rowok && ((unsigned)j < (unsigned)TT);                  \
      float r0 = softmin_cell(d0, up0v, cur0, diag0v);                   \
      float r1 = softmin_cell(d1, r0, cur1, oc0);                        \
      float r2 = softmin_cell(d2, r1, cur2, oc1);                        \
      float r3 = softmin_cell(d3, r2, cur3, oc2);                        \
      cur0 = act ? r0 : INFV; cur1 = act ? r1 : INFV;                    \
      cur2 = act ? r2 : INFV; cur3 = act ? r3 : INFV;                    \
      if (w < 3) {                                                       \
        if (lane == 63 && (unsigned)(u - 63) < (unsigned)TT)             \
          bnd[w][(u - 63) & 127] = cur3;                                 \
      } else if (lane == 7 && u == 806) {                                \
        atomicAdd(&out[which], cur3 * 6.25e-5f);                         \
      }                                                                  \
    } } while (0)

  for (int G = 0; G < NGC; ++G) {
    const int lc = G - LAG * w;
    if (lc >= 0 && lc <= NLC - 1) {
      const int u0 = lc * KSTEP;
      if (lc == 0) LOADG(bufA, 0);
      LOADG(bufB, u0 + 8);  STEP8(bufA, u0);
      LOADG(bufA, u0 + 16); STEP8(bufB, u0 + 8);
      LOADG(bufB, u0 + 24); STEP8(bufA, u0 + 16);
      LOADG(bufA, u0 + 32); STEP8(bufB, u0 + 24);
    }
    __syncthreads();  // publishes bnd ring across bands
  }
#undef LOADG
#undef STEP8
}

extern "C" void kernel_launch(void* const* d_in, const int* in_sizes, int n_in,
                              void* d_out, int out_size, void* d_ws, size_t ws_size,
                              hipStream_t stream) {
  const float* d         = (const float*)d_in[0];
  const int*   mel_len   = (const int*)d_in[1];
  const float* mel       = (const float*)d_in[2];
  const float* post      = (const float*)d_in[3];
  const float* target    = (const float*)d_in[4];
  const void*  src_mask  = d_in[5];
  const void*  pred_mask = d_in[6];
  float* out = (float*)d_out;

  int* flags = (int*)d_ws;
  __half* Dsk = (__half*)((char*)d_ws + 256);
  size_t per = (size_t)4 * UPAD * 256 * sizeof(__half);  // 1.77 MB per problem
  int slots = 0;
  if (ws_size > 256) slots = (int)((ws_size - 256) / per);
  if (slots > 32) slots = 32;

  (void)hipMemsetAsync(d_out, 0, 3 * sizeof(float), stream);
  detect_dloss_kernel<<<1, 256, 0, stream>>>(d, mel_len, src_mask, pred_mask, flags, out);
  if (slots < 1) return;

  for (int base = 0; base < 32; base += slots) {
    int g = (32 - base < slots) ? (32 - base) : slots;
    cost_kernel<<<dim3(13, 13, g), 256, 0, stream>>>(mel, post, target, pred_mask,
                                                     flags, Dsk, base);
    dtw_kernel<<<g, 256, 0, stream>>>(Dsk, out, base);
  }
}

// Round 4
// 496.881 us; speedup vs baseline: 2.6548x; 1.2896x over previous
//
#include <hip/hip_runtime.h>
#include <hip/hip_fp16.h>

#define TT 800
#define CC 80
#define BB 16
#define SS 128
#define INFV 1e9f
#define NLCB 113          // local chunks per band (904 steps / 8)
#define LAGCH 14          // chunk lag between bands (112 steps >= 98 + 8 + margin)
#define NGC 155           // 113 + 3*14
#define BANDH 200         // rows per band (4 bands x 200 = 800)
#define HALF_PER_BAND (113*50*32)     // 180800
#define HALF_PER_SLOT (4*113*50*32)   // 723200

// Bool masks may arrive as 1-byte numpy bools or int32 — detected at runtime.
__device__ inline bool mask_get(const void* p, int idx, int isInt) {
  if (isInt) return ((const int*)p)[idx] != 0;
  return ((const unsigned char*)p)[idx] != 0;
}

__device__ __forceinline__ float fexp2(float x) {
#if __has_builtin(__builtin_amdgcn_exp2f)
  return __builtin_amdgcn_exp2f(x);
#else
  return __expf(x * 0.6931471805599453f);
#endif
}
__device__ __forceinline__ float flog2(float x) {
#if __has_builtin(__builtin_amdgcn_logf)
  return __builtin_amdgcn_logf(x);
#else
  return __logf(x) * 1.4426950408889634f;
#endif
}
__device__ __forceinline__ float fmed3(float a, float b, float c) {
#if __has_builtin(__builtin_amdgcn_fmed3f)
  return __builtin_amdgcn_fmed3f(a, b, c);
#else
  return fmaxf(fminf(a, b), fminf(fmaxf(a, b), c));
#endif
}

// softmin3 with gamma=0.1: mn - g*ln(1 + e^{(mn-md)/g} + e^{(mn-mx)/g}) + d
__device__ __forceinline__ float cellf(float d, float a, float b, float c) {
  float mn = fminf(fminf(a, b), c);
  float mx = fmaxf(fmaxf(a, b), c);
  float md = fmed3(a, b, c);
  const float SC = 14.426950408889634f;   // (1/gamma)*log2(e)
  float e1 = fexp2((mn - md) * SC);
  float e2 = fexp2((mn - mx) * SC);
  float s = 1.0f + e1 + e2;
  return fmaf(flog2(s), -0.06931471805599453f, d + mn);  // -gamma*ln2
}

// Single block: detect mask element width, compute d_loss into out[2].
__global__ __launch_bounds__(256) void detect_dloss_kernel(
    const float* __restrict__ d, const int* __restrict__ mel_len,
    const void* __restrict__ src_mask, const void* __restrict__ pred_mask,
    int* __restrict__ flags, float* __restrict__ out)
{
  __shared__ int nzs, nzp;
  __shared__ float lb[BB];
  int tid = threadIdx.x;
  if (tid == 0) { nzs = 0; nzp = 0; }
  __syncthreads();
  const unsigned char* sm = (const unsigned char*)src_mask;
  const unsigned char* pm = (const unsigned char*)pred_mask;
  int f = 0;
  for (int i = tid; i < BB * SS; i += 256) if ((i & 3) && sm[i]) f = 1;
  if (f) atomicOr(&nzs, 1);
  f = 0;
  for (int i = tid; i < BB * TT; i += 256) if ((i & 3) && pm[i]) f = 1;
  if (f) atomicOr(&nzp, 1);
  __syncthreads();
  int isIntS = nzs ? 0 : 1;
  if (tid == 0) { flags[0] = isIntS; flags[1] = nzp ? 0 : 1; }

  int b = tid >> 4, k = tid & 15;
  float sd = 0.f, so = 0.f;
  for (int s = k; s < SS; s += 16) {
    bool m = mask_get(src_mask, b * SS + s, isIntS);
    if (!m) { sd += d[b * SS + s]; so += 1.f; }
  }
  for (int off = 8; off; off >>= 1) {
    sd += __shfl_down(sd, off, 16);
    so += __shfl_down(so, off, 16);
  }
  if (k == 0) lb[b] = fabsf((float)mel_len[b] - sd) / so;
  __syncthreads();
  if (tid == 0) {
    float s = 0.f;
    for (int i = 0; i < BB; i++) s += lb[i];
    out[2] = s / (float)BB;
  }
}

// Cost matrix, written in chunk-transposed skew-2 layout:
// Dsk[slot][band][chunk][lane][step_in_chunk][4 rows] halfs, where for element
// (i,j): band=i/200, l=(i%200)>>2, rr=i&3, s=j+2l, chunk=s>>3, k=s&7.
__global__ __launch_bounds__(256) void cost_kernel(
    const float* __restrict__ mel, const float* __restrict__ post,
    const float* __restrict__ target, const void* __restrict__ pred_mask,
    const int* __restrict__ flags, __half* __restrict__ Dsk, int probBase)
{
  int slot = blockIdx.z;
  int prob = probBase + slot;
  int which = prob >> 4, b = prob & 15;
  const float* X = (which ? post : mel) + (size_t)b * TT * CC;
  const float* Y = target + (size_t)b * TT * CC;
  int i0 = blockIdx.y * 64, j0 = blockIdx.x * 64;
  int isInt = flags[1];

  __shared__ __attribute__((aligned(16))) float As[16][68];
  __shared__ __attribute__((aligned(16))) float Bs[16][68];

  int tid = threadIdx.x;
  int kk = tid & 15, r4 = tid >> 4;   // staging roles
  int tx = tid & 15, ty = tid >> 4;   // compute roles
  float acc[4][4] = {};

  for (int kc = 0; kc < CC; kc += 16) {
    __syncthreads();
#pragma unroll
    for (int q = 0; q < 4; q++) {
      int i = r4 + q * 16;
      int gia = i0 + i, gib = j0 + i;
      float xs = 0.f, ys = 0.f;
      if (gia < TT) {
        float v = X[(size_t)gia * CC + kc + kk];
        if (which == 0 && mask_get(pred_mask, b * TT + gia, isInt)) v = 0.f;
        xs = 1.f / (1.f + __expf(-v));
      }
      if (gib < TT) {
        float wv = Y[(size_t)gib * CC + kc + kk];
        ys = 1.f / (1.f + __expf(-wv));
      }
      As[kk][i] = xs;
      Bs[kk][i] = ys;
    }
    __syncthreads();
#pragma unroll
    for (int k = 0; k < 16; k++) {
      float4 a4 = *(const float4*)&As[k][ty * 4];
      float4 b4 = *(const float4*)&Bs[k][tx * 4];
      float am[4] = {a4.x, a4.y, a4.z, a4.w};
      float bn[4] = {b4.x, b4.y, b4.z, b4.w};
#pragma unroll
      for (int m = 0; m < 4; m++)
#pragma unroll
        for (int n = 0; n < 4; n++) {
          float df = am[m] - bn[n];
          acc[m][n] = fmaf(df, df, acc[m][n]);
        }
    }
  }

  // epilogue: store each thread's 4x4 quad directly to the skewed layout
  int i4 = i0 + ty * 4;
  if (i4 < TT) {
    int band = i4 / BANDH;
    int l = (i4 % BANDH) >> 2;
    __half* base = Dsk + (size_t)slot * HALF_PER_SLOT + (size_t)band * HALF_PER_BAND;
#pragma unroll
    for (int n = 0; n < 4; n++) {
      int j = j0 + tx * 4 + n;
      if (j < TT) {
        int s = j + 2 * l;
        int ch = s >> 3, k = s & 7;
        union { __half h[4]; uint2 u; } cv;
#pragma unroll
        for (int m = 0; m < 4; m++) cv.h[m] = __float2half(acc[m][n]);
        *(uint2*)(base + ((size_t)(ch * 50 + l)) * 32 + k * 4) = cv.u;
      }
    }
  }
}

// Wave-pipelined soft-DTW: 4 waves = 4 bands of 200 rows (lanes 0..49, 4 rows
// each), skew-2 (lane l at col j = s-2l) so the cross-lane shfl is consumed one
// step after issue (latency hidden). Ring traffic batched per 8-step chunk.
__global__ __launch_bounds__(256) void dtw_kernel(
    const __half* __restrict__ Dsk, float* __restrict__ out, int probBase)
{
  __shared__ float bnd[3][128];
  const int tid = threadIdx.x;
  const int w = tid >> 6, lane = tid & 63;
  const int slot = blockIdx.x;
  const int prob = probBase + slot;
  const int which = prob >> 4;
  const int lclamp = lane < 49 ? lane : 49;
  const __half* Db = Dsk + (size_t)slot * HALF_PER_SLOT + (size_t)w * HALF_PER_BAND;

  float cur0 = INFV, cur1 = INFV, cur2 = INFV, cur3 = INFV;
  float up_pipe = INFV, up_prev = INFV, rcarry = INFV, res = 0.f;
  float rbv[8], wrv[8];
#pragma unroll
  for (int k = 0; k < 8; k++) { rbv[k] = INFV; wrv[k] = INFV; }

  uint4 a0, a1, a2, a3, b0, b1, b2, b3;

#define PRE(P0, P1, P2, P3, LCN) do { if ((LCN) < NLCB) {                     \
    const uint4* p_ = (const uint4*)(Db + ((size_t)(LCN) * 50 + lclamp) * 32);\
    P0 = p_[0]; P1 = p_[1]; P2 = p_[2]; P3 = p_[3]; } } while (0)

#define RINGLOAD do { if (w) {                                                \
    const float4* rp_ = (const float4*)&bnd[w - 1][s0 & 127];                 \
    float4 ra_ = rp_[0], rc_ = rp_[1];                                        \
    rbv[0] = ra_.x; rbv[1] = ra_.y; rbv[2] = ra_.z; rbv[3] = ra_.w;           \
    rbv[4] = rc_.x; rbv[5] = rc_.y; rbv[6] = rc_.z; rbv[7] = rc_.w; } } while (0)

#define DO_STEP(K, LOU, HIU) do {                                             \
    const int s_ = s0 + (K);                                                  \
    float nxt_ = __shfl_up(cur3, 1, 64);                                      \
    unsigned lou_ = (LOU), hiu_ = (HIU);                                      \
    float2 f01 = __half22float2(*(const __half2*)&lou_);                      \
    float2 f23 = __half22float2(*(const __half2*)&hiu_);                      \
    float up_ = up_pipe, dg_ = up_prev;                                       \
    if (w == 0) { if (lane == 0) { up_ = INFV; dg_ = (s_ == 0) ? 0.0f : INFV; } } \
    else if (lane == 0) { up_ = rbv[(K)]; dg_ = ((K) == 0) ? rcarry : rbv[(K) == 0 ? 0 : (K) - 1]; } \
    float oc0 = cur0, oc1 = cur1, oc2 = cur2;                                 \
    float r0 = cellf(f01.x, up_, cur0, dg_);                                  \
    float r1 = cellf(f01.y, r0, cur1, oc0);                                   \
    float r2 = cellf(f23.x, r1, cur2, oc1);                                   \
    float r3 = cellf(f23.y, r2, cur3, oc2);                                   \
    int j_ = s_ - 2 * lane;                                                   \
    bool act_ = (lane < 50) && ((unsigned)j_ < 800u);                         \
    cur0 = act_ ? r0 : INFV; cur1 = act_ ? r1 : INFV;                         \
    cur2 = act_ ? r2 : INFV; cur3 = act_ ? r3 : INFV;                         \
    wrv[(K)] = cur3;                                                          \
    if (s_ == 897) res = cur3;                                                \
    up_prev = up_pipe; up_pipe = nxt_;                                        \
  } while (0)

#define STEP8(Q0, Q1, Q2, Q3) do {                                            \
    DO_STEP(0, Q0.x, Q0.y); DO_STEP(1, Q0.z, Q0.w);                           \
    DO_STEP(2, Q1.x, Q1.y); DO_STEP(3, Q1.z, Q1.w);                           \
    DO_STEP(4, Q2.x, Q2.y); DO_STEP(5, Q2.z, Q2.w);                           \
    DO_STEP(6, Q3.x, Q3.y); DO_STEP(7, Q3.z, Q3.w); } while (0)

  // prologue: every wave loads its local chunk 0
  PRE(a0, a1, a2, a3, 0);
  __syncthreads();

  for (int G = 0; G < NGC; ++G) {
    const int lc = G - LAGCH * w;
    if (lc >= 0 && lc < NLCB) {
      const int s0 = lc << 3;
      if ((lc & 1) == 0) {
        PRE(b0, b1, b2, b3, lc + 1);
        RINGLOAD;
        STEP8(a0, a1, a2, a3);
      } else {
        PRE(a0, a1, a2, a3, lc + 1);
        RINGLOAD;
        STEP8(b0, b1, b2, b3);
      }
      if (w < 3 && lane == 49) {
#pragma unroll
        for (int k = 0; k < 8; k++) {
          int j = s0 + k - 98;
          if ((unsigned)j < 800u) bnd[w][j & 127] = wrv[k];
        }
      }
      rcarry = rbv[7];
    }
    __syncthreads();
  }

  if (w == 3 && lane == 49) atomicAdd(&out[which], res * 6.25e-5f);

#undef PRE
#undef RINGLOAD
#undef DO_STEP
#undef STEP8
}

extern "C" void kernel_launch(void* const* d_in, const int* in_sizes, int n_in,
                              void* d_out, int out_size, void* d_ws, size_t ws_size,
                              hipStream_t stream) {
  const float* d         = (const float*)d_in[0];
  const int*   mel_len   = (const int*)d_in[1];
  const float* mel       = (const float*)d_in[2];
  const float* post      = (const float*)d_in[3];
  const float* target    = (const float*)d_in[4];
  const void*  src_mask  = d_in[5];
  const void*  pred_mask = d_in[6];
  float* out = (float*)d_out;

  int* flags = (int*)d_ws;
  __half* Dsk = (__half*)((char*)d_ws + 256);
  size_t per = (size_t)HALF_PER_SLOT * sizeof(__half);  // 1.446 MB per problem
  int slots = 0;
  if (ws_size > 256) slots = (int)((ws_size - 256) / per);
  if (slots > 32) slots = 32;

  (void)hipMemsetAsync(d_out, 0, 3 * sizeof(float), stream);
  detect_dloss_kernel<<<1, 256, 0, stream>>>(d, mel_len, src_mask, pred_mask, flags, out);
  if (slots < 1) return;

  for (int base = 0; base < 32; base += slots) {
    int g = (32 - base < slots) ? (32 - base) : slots;
    cost_kernel<<<dim3(13, 13, g), 256, 0, stream>>>(mel, post, target, pred_mask,
                                                     flags, Dsk, base);
    dtw_kernel<<<g, 256, 0, stream>>>(Dsk, out, base);
  }
}

// Round 5
// 476.143 us; speedup vs baseline: 2.7704x; 1.0436x over previous
//
#include <hip/hip_runtime.h>
#include <hip/hip_fp16.h>

#define TT 800
#define CC 80
#define BB 16
#define SS 128
#define INFV 1e9f
#define NLCB 113          // local chunks per band (904 steps / 8)
#define LAGCH 14          // chunk lag between bands (112 steps >= 98 + 8 + margin)
#define NGC 155           // 113 + 3*14
#define BANDH 200         // rows per band (4 bands x 200 = 800)
#define HALF_PER_BAND (113*50*32)     // 180800
#define HALF_PER_SLOT (4*113*50*32)   // 723200
#define SCALE 14.426950408889634f     // (1/gamma)*log2(e), gamma=0.1

// Bool masks may arrive as 1-byte numpy bools or int32 — detected at runtime.
__device__ inline bool mask_get(const void* p, int idx, int isInt) {
  if (isInt) return ((const int*)p)[idx] != 0;
  return ((const unsigned char*)p)[idx] != 0;
}

__device__ __forceinline__ float fexp2(float x) {
#if __has_builtin(__builtin_amdgcn_exp2f)
  return __builtin_amdgcn_exp2f(x);
#else
  return __expf(x * 0.6931471805599453f);
#endif
}
__device__ __forceinline__ float flog2(float x) {
#if __has_builtin(__builtin_amdgcn_logf)
  return __builtin_amdgcn_logf(x);
#else
  return __logf(x) * 1.4426950408889634f;
#endif
}
__device__ __forceinline__ float fmed3(float a, float b, float c) {
#if __has_builtin(__builtin_amdgcn_fmed3f)
  return __builtin_amdgcn_fmed3f(a, b, c);
#else
  return fmaxf(fminf(a, b), fminf(fmaxf(a, b), c));
#endif
}

// Pre-scaled softmin3 (inputs are R*SCALE, d is D*SCALE):
// r' = d' + mn' - log2(1 + 2^(mn'-md') + 2^(mn'-mx'))
// since gamma*ln2*SCALE == 1. No multiplies on the chain.
__device__ __forceinline__ float cellf(float d, float a, float b, float c) {
  float mn = fminf(fminf(a, b), c);
  float mx = fmaxf(fmaxf(a, b), c);
  float md = fmed3(a, b, c);
  float e1 = fexp2(mn - md);
  float e2 = fexp2(mn - mx);
  float s = 1.0f + e1 + e2;
  return (d + mn) - flog2(s);
}

// Single block: detect mask element width, compute d_loss into out[2].
__global__ __launch_bounds__(256) void detect_dloss_kernel(
    const float* __restrict__ d, const int* __restrict__ mel_len,
    const void* __restrict__ src_mask, const void* __restrict__ pred_mask,
    int* __restrict__ flags, float* __restrict__ out)
{
  __shared__ int nzs, nzp;
  __shared__ float lb[BB];
  int tid = threadIdx.x;
  if (tid == 0) { nzs = 0; nzp = 0; }
  __syncthreads();
  const unsigned char* sm = (const unsigned char*)src_mask;
  const unsigned char* pm = (const unsigned char*)pred_mask;
  int f = 0;
  for (int i = tid; i < BB * SS; i += 256) if ((i & 3) && sm[i]) f = 1;
  if (f) atomicOr(&nzs, 1);
  f = 0;
  for (int i = tid; i < BB * TT; i += 256) if ((i & 3) && pm[i]) f = 1;
  if (f) atomicOr(&nzp, 1);
  __syncthreads();
  int isIntS = nzs ? 0 : 1;
  if (tid == 0) { flags[0] = isIntS; flags[1] = nzp ? 0 : 1; }

  int b = tid >> 4, k = tid & 15;
  float sd = 0.f, so = 0.f;
  for (int s = k; s < SS; s += 16) {
    bool m = mask_get(src_mask, b * SS + s, isIntS);
    if (!m) { sd += d[b * SS + s]; so += 1.f; }
  }
  for (int off = 8; off; off >>= 1) {
    sd += __shfl_down(sd, off, 16);
    so += __shfl_down(so, off, 16);
  }
  if (k == 0) lb[b] = fabsf((float)mel_len[b] - sd) / so;
  __syncthreads();
  if (tid == 0) {
    float s = 0.f;
    for (int i = 0; i < BB; i++) s += lb[i];
    out[2] = s / (float)BB;
  }
}

// Cost matrix (pre-scaled by SCALE), chunk-transposed skew-2 layout:
// Dsk[slot][band][chunk][lane][step_in_chunk][4 rows] halfs, where for element
// (i,j): band=i/200, l=(i%200)>>2, rr=i&3, s=j+2l, chunk=s>>3, k=s&7.
__global__ __launch_bounds__(256) void cost_kernel(
    const float* __restrict__ mel, const float* __restrict__ post,
    const float* __restrict__ target, const void* __restrict__ pred_mask,
    const int* __restrict__ flags, __half* __restrict__ Dsk, int probBase)
{
  int slot = blockIdx.z;
  int prob = probBase + slot;
  int which = prob >> 4, b = prob & 15;
  const float* X = (which ? post : mel) + (size_t)b * TT * CC;
  const float* Y = target + (size_t)b * TT * CC;
  int i0 = blockIdx.y * 64, j0 = blockIdx.x * 64;
  int isInt = flags[1];

  __shared__ __attribute__((aligned(16))) float As[16][68];
  __shared__ __attribute__((aligned(16))) float Bs[16][68];

  int tid = threadIdx.x;
  int kk = tid & 15, r4 = tid >> 4;   // staging roles
  int tx = tid & 15, ty = tid >> 4;   // compute roles
  float acc[4][4] = {};

  for (int kc = 0; kc < CC; kc += 16) {
    __syncthreads();
#pragma unroll
    for (int q = 0; q < 4; q++) {
      int i = r4 + q * 16;
      int gia = i0 + i, gib = j0 + i;
      float xs = 0.f, ys = 0.f;
      if (gia < TT) {
        float v = X[(size_t)gia * CC + kc + kk];
        if (which == 0 && mask_get(pred_mask, b * TT + gia, isInt)) v = 0.f;
        xs = 1.f / (1.f + __expf(-v));
      }
      if (gib < TT) {
        float wv = Y[(size_t)gib * CC + kc + kk];
        ys = 1.f / (1.f + __expf(-wv));
      }
      As[kk][i] = xs;
      Bs[kk][i] = ys;
    }
    __syncthreads();
#pragma unroll
    for (int k = 0; k < 16; k++) {
      float4 a4 = *(const float4*)&As[k][ty * 4];
      float4 b4 = *(const float4*)&Bs[k][tx * 4];
      float am[4] = {a4.x, a4.y, a4.z, a4.w};
      float bn[4] = {b4.x, b4.y, b4.z, b4.w};
#pragma unroll
      for (int m = 0; m < 4; m++)
#pragma unroll
        for (int n = 0; n < 4; n++) {
          float df = am[m] - bn[n];
          acc[m][n] = fmaf(df, df, acc[m][n]);
        }
    }
  }

  // epilogue: store each thread's 4x4 quad (pre-scaled) to the skewed layout
  int i4 = i0 + ty * 4;
  if (i4 < TT) {
    int band = i4 / BANDH;
    int l = (i4 % BANDH) >> 2;
    __half* base = Dsk + (size_t)slot * HALF_PER_SLOT + (size_t)band * HALF_PER_BAND;
#pragma unroll
    for (int n = 0; n < 4; n++) {
      int j = j0 + tx * 4 + n;
      if (j < TT) {
        int s = j + 2 * l;
        int ch = s >> 3, k = s & 7;
        union { __half h[4]; uint2 u; } cv;
#pragma unroll
        for (int m = 0; m < 4; m++) cv.h[m] = __float2half(acc[m][n] * SCALE);
        *(uint2*)(base + ((size_t)(ch * 50 + l)) * 32 + k * 4) = cv.u;
      }
    }
  }
}

// Wave-pipelined soft-DTW (pre-scaled domain): 4 waves = 4 bands of 200 rows
// (lanes 0..49, 4 rows each), skew-2 so the cross-lane shfl is consumed one
// step after issue. Ring traffic batched per 8-step chunk.
__global__ __launch_bounds__(256) void dtw_kernel(
    const __half* __restrict__ Dsk, float* __restrict__ out, int probBase)
{
  __shared__ float bnd[3][128];
  const int tid = threadIdx.x;
  const int w = tid >> 6, lane = tid & 63;
  const int slot = blockIdx.x;
  const int prob = probBase + slot;
  const int which = prob >> 4;
  const int lclamp = lane < 49 ? lane : 49;
  const __half* Db = Dsk + (size_t)slot * HALF_PER_SLOT + (size_t)w * HALF_PER_BAND;

  float cur0 = INFV, cur1 = INFV, cur2 = INFV, cur3 = INFV;
  float up_pipe = INFV, up_prev = INFV, rcarry = INFV, res = 0.f;
  float rbv[8], wrv[8];
#pragma unroll
  for (int k = 0; k < 8; k++) { rbv[k] = INFV; wrv[k] = INFV; }

  uint4 a0, a1, a2, a3, b0, b1, b2, b3;

#define PRE(P0, P1, P2, P3, LCN) do { if ((LCN) < NLCB) {                     \
    const uint4* p_ = (const uint4*)(Db + ((size_t)(LCN) * 50 + lclamp) * 32);\
    P0 = p_[0]; P1 = p_[1]; P2 = p_[2]; P3 = p_[3]; } } while (0)

#define RINGLOAD do { if (w) {                                                \
    const float4* rp_ = (const float4*)&bnd[w - 1][s0 & 127];                 \
    float4 ra_ = rp_[0], rc_ = rp_[1];                                        \
    rbv[0] = ra_.x; rbv[1] = ra_.y; rbv[2] = ra_.z; rbv[3] = ra_.w;           \
    rbv[4] = rc_.x; rbv[5] = rc_.y; rbv[6] = rc_.z; rbv[7] = rc_.w; } } while (0)

#define DO_STEP(K, LOU, HIU) do {                                             \
    const int s_ = s0 + (K);                                                  \
    float nxt_ = __shfl_up(cur3, 1, 64);                                      \
    unsigned lou_ = (LOU), hiu_ = (HIU);                                      \
    float2 f01 = __half22float2(*(const __half2*)&lou_);                      \
    float2 f23 = __half22float2(*(const __half2*)&hiu_);                      \
    float up_ = up_pipe, dg_ = up_prev;                                       \
    if (w == 0) { if (lane == 0) { up_ = INFV; dg_ = (s_ == 0) ? 0.0f : INFV; } } \
    else if (lane == 0) { up_ = rbv[(K)]; dg_ = ((K) == 0) ? rcarry : rbv[(K) == 0 ? 0 : (K) - 1]; } \
    float oc0 = cur0, oc1 = cur1, oc2 = cur2;                                 \
    float r0 = cellf(f01.x, up_, cur0, dg_);                                  \
    float r1 = cellf(f01.y, r0, cur1, oc0);                                   \
    float r2 = cellf(f23.x, r1, cur2, oc1);                                   \
    float r3 = cellf(f23.y, r2, cur3, oc2);                                   \
    int j_ = s_ - 2 * lane;                                                   \
    bool act_ = (lane < 50) && ((unsigned)j_ < 800u);                         \
    cur0 = act_ ? r0 : INFV; cur1 = act_ ? r1 : INFV;                         \
    cur2 = act_ ? r2 : INFV; cur3 = act_ ? r3 : INFV;                         \
    wrv[(K)] = cur3;                                                          \
    if (s_ == 897) res = cur3;                                                \
    up_prev = up_pipe; up_pipe = nxt_;                                        \
  } while (0)

#define STEP8(Q0, Q1, Q2, Q3) do {                                            \
    DO_STEP(0, Q0.x, Q0.y); DO_STEP(1, Q0.z, Q0.w);                           \
    DO_STEP(2, Q1.x, Q1.y); DO_STEP(3, Q1.z, Q1.w);                           \
    DO_STEP(4, Q2.x, Q2.y); DO_STEP(5, Q2.z, Q2.w);                           \
    DO_STEP(6, Q3.x, Q3.y); DO_STEP(7, Q3.z, Q3.w); } while (0)

  // prologue: every wave loads its local chunk 0
  PRE(a0, a1, a2, a3, 0);
  __syncthreads();

  for (int G = 0; G < NGC; ++G) {
    const int lc = G - LAGCH * w;
    if (lc >= 0 && lc < NLCB) {
      const int s0 = lc << 3;
      if ((lc & 1) == 0) {
        PRE(b0, b1, b2, b3, lc + 1);
        RINGLOAD;
        STEP8(a0, a1, a2, a3);
      } else {
        PRE(a0, a1, a2, a3, lc + 1);
        RINGLOAD;
        STEP8(b0, b1, b2, b3);
      }
      if (w < 3 && lane == 49) {
#pragma unroll
        for (int k = 0; k < 8; k++) {
          int j = s0 + k - 98;
          if ((unsigned)j < 800u) bnd[w][j & 127] = wrv[k];
        }
      }
      rcarry = rbv[7];
    }
    __syncthreads();
  }

  // res is pre-scaled; unscale (1/SCALE) and apply 0.001/16 in one constant.
  if (w == 3 && lane == 49) atomicAdd(&out[which], res * 4.3321699e-6f);

#undef PRE
#undef RINGLOAD
#undef DO_STEP
#undef STEP8
}

extern "C" void kernel_launch(void* const* d_in, const int* in_sizes, int n_in,
                              void* d_out, int out_size, void* d_ws, size_t ws_size,
                              hipStream_t stream) {
  const float* d         = (const float*)d_in[0];
  const int*   mel_len   = (const int*)d_in[1];
  const float* mel       = (const float*)d_in[2];
  const float* post      = (const float*)d_in[3];
  const float* target    = (const float*)d_in[4];
  const void*  src_mask  = d_in[5];
  const void*  pred_mask = d_in[6];
  float* out = (float*)d_out;

  int* flags = (int*)d_ws;
  __half* Dsk = (__half*)((char*)d_ws + 256);
  size_t per = (size_t)HALF_PER_SLOT * sizeof(__half);  // 1.446 MB per problem
  int slots = 0;
  if (ws_size > 256) slots = (int)((ws_size - 256) / per);
  if (slots > 32) slots = 32;

  (void)hipMemsetAsync(d_out, 0, 3 * sizeof(float), stream);
  detect_dloss_kernel<<<1, 256, 0, stream>>>(d, mel_len, src_mask, pred_mask, flags, out);
  if (slots < 1) return;

  for (int base = 0; base < 32; base += slots) {
    int g = (32 - base < slots) ? (32 - base) : slots;
    cost_kernel<<<dim3(13, 13, g), 256, 0, stream>>>(mel, post, target, pred_mask,
                                                     flags, Dsk, base);
    dtw_kernel<<<g, 256, 0, stream>>>(Dsk, out, base);
  }
}

// Round 6
// 446.146 us; speedup vs baseline: 2.9567x; 1.0672x over previous
//
#include <hip/hip_runtime.h>
#include <hip/hip_fp16.h>

#define TT 800
#define CC 80
#define BB 16
#define SS 128
#define INFV 1e9f
#define NLCB 107          // local chunks per band: steps 0..855 cover s<=848
#define LAGCH 8           // chunk lag between bands (64 steps >= 49+8+margin)
#define NGC 163           // 107 + 7*8
#define BANDH 100         // rows per band (8 bands x 100 = 800)
#define HALF_PER_BAND (107*50*16)     // 85600
#define HALF_PER_SLOT (8*107*50*16)   // 684800
#define SCALE 14.426950408889634f     // (1/gamma)*log2(e), gamma=0.1

// Bool masks may arrive as 1-byte numpy bools or int32 — detected at runtime.
__device__ inline bool mask_get(const void* p, int idx, int isInt) {
  if (isInt) return ((const int*)p)[idx] != 0;
  return ((const unsigned char*)p)[idx] != 0;
}

__device__ __forceinline__ float fexp2(float x) {
#if __has_builtin(__builtin_amdgcn_exp2f)
  return __builtin_amdgcn_exp2f(x);
#else
  return __expf(x * 0.6931471805599453f);
#endif
}
__device__ __forceinline__ float flog2(float x) {
#if __has_builtin(__builtin_amdgcn_logf)
  return __builtin_amdgcn_logf(x);
#else
  return __logf(x) * 1.4426950408889634f;
#endif
}
__device__ __forceinline__ float fmed3(float a, float b, float c) {
#if __has_builtin(__builtin_amdgcn_fmed3f)
  return __builtin_amdgcn_fmed3f(a, b, c);
#else
  return fmaxf(fminf(a, b), fminf(fmaxf(a, b), c));
#endif
}

// Pre-scaled softmin3 (inputs are R*SCALE, d is D*SCALE):
// r' = d' + mn' - log2(1 + 2^(mn'-md') + 2^(mn'-mx'))
__device__ __forceinline__ float cellf(float d, float a, float b, float c) {
  float mn = fminf(fminf(a, b), c);
  float mx = fmaxf(fmaxf(a, b), c);
  float md = fmed3(a, b, c);
  float e1 = fexp2(mn - md);
  float e2 = fexp2(mn - mx);
  float s = 1.0f + e1 + e2;
  return (d + mn) - flog2(s);
}

// Single block: detect mask element width, compute d_loss into out[2].
__global__ __launch_bounds__(256) void detect_dloss_kernel(
    const float* __restrict__ d, const int* __restrict__ mel_len,
    const void* __restrict__ src_mask, const void* __restrict__ pred_mask,
    int* __restrict__ flags, float* __restrict__ out)
{
  __shared__ int nzs, nzp;
  __shared__ float lb[BB];
  int tid = threadIdx.x;
  if (tid == 0) { nzs = 0; nzp = 0; }
  __syncthreads();
  const unsigned char* sm = (const unsigned char*)src_mask;
  const unsigned char* pm = (const unsigned char*)pred_mask;
  int f = 0;
  for (int i = tid; i < BB * SS; i += 256) if ((i & 3) && sm[i]) f = 1;
  if (f) atomicOr(&nzs, 1);
  f = 0;
  for (int i = tid; i < BB * TT; i += 256) if ((i & 3) && pm[i]) f = 1;
  if (f) atomicOr(&nzp, 1);
  __syncthreads();
  int isIntS = nzs ? 0 : 1;
  if (tid == 0) { flags[0] = isIntS; flags[1] = nzp ? 0 : 1; }

  int b = tid >> 4, k = tid & 15;
  float sd = 0.f, so = 0.f;
  for (int s = k; s < SS; s += 16) {
    bool m = mask_get(src_mask, b * SS + s, isIntS);
    if (!m) { sd += d[b * SS + s]; so += 1.f; }
  }
  for (int off = 8; off; off >>= 1) {
    sd += __shfl_down(sd, off, 16);
    so += __shfl_down(so, off, 16);
  }
  if (k == 0) lb[b] = fabsf((float)mel_len[b] - sd) / so;
  __syncthreads();
  if (tid == 0) {
    float s = 0.f;
    for (int i = 0; i < BB; i++) s += lb[i];
    out[2] = s / (float)BB;
  }
}

// Cost matrix (pre-scaled by SCALE), skew-1 chunked layout:
// Dsk[slot][band8][chunk107][lane50][step8][row2] halfs; for element (i,j):
// band=i/100, l=(i%100)>>1, rr=i&1, s=j+l, chunk=s>>3, k=s&7.
__global__ __launch_bounds__(256) void cost_kernel(
    const float* __restrict__ mel, const float* __restrict__ post,
    const float* __restrict__ target, const void* __restrict__ pred_mask,
    const int* __restrict__ flags, __half* __restrict__ Dsk, int probBase)
{
  int slot = blockIdx.z;
  int prob = probBase + slot;
  int which = prob >> 4, b = prob & 15;
  const float* X = (which ? post : mel) + (size_t)b * TT * CC;
  const float* Y = target + (size_t)b * TT * CC;
  int i0 = blockIdx.y * 64, j0 = blockIdx.x * 64;
  int isInt = flags[1];

  __shared__ __attribute__((aligned(16))) float As[16][68];
  __shared__ __attribute__((aligned(16))) float Bs[16][68];

  int tid = threadIdx.x;
  int kk = tid & 15, r4 = tid >> 4;   // staging roles
  int tx = tid & 15, ty = tid >> 4;   // compute roles
  float acc[4][4] = {};

  for (int kc = 0; kc < CC; kc += 16) {
    __syncthreads();
#pragma unroll
    for (int q = 0; q < 4; q++) {
      int i = r4 + q * 16;
      int gia = i0 + i, gib = j0 + i;
      float xs = 0.f, ys = 0.f;
      if (gia < TT) {
        float v = X[(size_t)gia * CC + kc + kk];
        if (which == 0 && mask_get(pred_mask, b * TT + gia, isInt)) v = 0.f;
        xs = 1.f / (1.f + __expf(-v));
      }
      if (gib < TT) {
        float wv = Y[(size_t)gib * CC + kc + kk];
        ys = 1.f / (1.f + __expf(-wv));
      }
      As[kk][i] = xs;
      Bs[kk][i] = ys;
    }
    __syncthreads();
#pragma unroll
    for (int k = 0; k < 16; k++) {
      float4 a4 = *(const float4*)&As[k][ty * 4];
      float4 b4 = *(const float4*)&Bs[k][tx * 4];
      float am[4] = {a4.x, a4.y, a4.z, a4.w};
      float bn[4] = {b4.x, b4.y, b4.z, b4.w};
#pragma unroll
      for (int m = 0; m < 4; m++)
#pragma unroll
        for (int n = 0; n < 4; n++) {
          float df = am[m] - bn[n];
          acc[m][n] = fmaf(df, df, acc[m][n]);
        }
    }
  }

  // epilogue: rows i4..i4+3 = lane pair (l0: rows 0,1) and (l0+1: rows 2,3)
  int i4 = i0 + ty * 4;
  if (i4 < TT) {
    int band = i4 / BANDH;
    int rem = i4 % BANDH;
    int l0 = rem >> 1;
    __half* base = Dsk + (size_t)slot * HALF_PER_SLOT + (size_t)band * HALF_PER_BAND;
#pragma unroll
    for (int n = 0; n < 4; n++) {
      int j = j0 + tx * 4 + n;
      if (j < TT) {
        union { __half h[2]; unsigned u; } p0, p1;
        p0.h[0] = __float2half(acc[0][n] * SCALE);
        p0.h[1] = __float2half(acc[1][n] * SCALE);
        p1.h[0] = __float2half(acc[2][n] * SCALE);
        p1.h[1] = __float2half(acc[3][n] * SCALE);
        int s0_ = j + l0;
        int s1_ = j + l0 + 1;
        *(unsigned*)(base + ((size_t)((s0_ >> 3) * 50 + l0)) * 16 + (s0_ & 7) * 2) = p0.u;
        *(unsigned*)(base + ((size_t)((s1_ >> 3) * 50 + l0 + 1)) * 16 + (s1_ & 7) * 2) = p1.u;
      }
    }
  }
}

// Wave-pipelined soft-DTW: 8 waves = 8 bands of 100 rows (lanes 0..49, 2 rows
// each), skew-1 (lane l at col j = s-l). 2 waves/SIMD so stalls overlap.
// Cross-wave boundary via LDS ring, barrier per 8-step chunk.
__global__ __launch_bounds__(512) void dtw_kernel(
    const __half* __restrict__ Dsk, float* __restrict__ out, int probBase)
{
  __shared__ float bnd[7][128];
  const int tid = threadIdx.x;
  const int w = tid >> 6, lane = tid & 63;
  const int slot = blockIdx.x;
  const int prob = probBase + slot;
  const int which = prob >> 4;
  const int lclamp = lane < 49 ? lane : 49;
  const __half* Db = Dsk + (size_t)slot * HALF_PER_SLOT + (size_t)w * HALF_PER_BAND;

  float cur0 = INFV, cur1 = INFV;
  float up_prev = INFV, rcarry = INFV, res = 0.f;
  float rbv[8], wrv[8];
#pragma unroll
  for (int k = 0; k < 8; k++) { rbv[k] = INFV; wrv[k] = INFV; }

  uint4 a0, a1, b0, b1;

#define PRE(P0, P1, LCN) do { if ((LCN) < NLCB) {                             \
    const uint4* p_ = (const uint4*)(Db + ((size_t)(LCN) * 50 + lclamp) * 16);\
    P0 = p_[0]; P1 = p_[1]; } } while (0)

#define RINGLOAD do { if (w) {                                                \
    const float4* rp_ = (const float4*)&bnd[w - 1][s0 & 127];                 \
    float4 ra_ = rp_[0], rc_ = rp_[1];                                        \
    rbv[0] = ra_.x; rbv[1] = ra_.y; rbv[2] = ra_.z; rbv[3] = ra_.w;           \
    rbv[4] = rc_.x; rbv[5] = rc_.y; rbv[6] = rc_.z; rbv[7] = rc_.w; } } while (0)

#define DO_STEP(K, UU) do {                                                   \
    const int s_ = s0 + (K);                                                  \
    float nxt_ = __shfl_up(cur1, 1, 64);                                      \
    unsigned uu_ = (UU);                                                      \
    float2 f01 = __half22float2(*(const __half2*)&uu_);                       \
    float up_ = nxt_, dg_ = up_prev;                                          \
    if (w == 0) { if (lane == 0) { up_ = INFV; dg_ = (s_ == 0) ? 0.0f : INFV; } } \
    else if (lane == 0) { up_ = rbv[(K)]; dg_ = ((K) == 0) ? rcarry : rbv[(K) == 0 ? 0 : (K) - 1]; } \
    float oc0 = cur0;                                                         \
    float r0 = cellf(f01.x, up_, cur0, dg_);                                  \
    float r1 = cellf(f01.y, r0, cur1, oc0);                                   \
    int j_ = s_ - lane;                                                       \
    bool act_ = (lane < 50) && ((unsigned)j_ < 800u);                         \
    cur0 = act_ ? r0 : INFV;                                                  \
    cur1 = act_ ? r1 : INFV;                                                  \
    wrv[(K)] = cur1;                                                          \
    if (s_ == 848) res = cur1;                                                \
    up_prev = nxt_;                                                           \
  } while (0)

#define STEP8(Q0, Q1) do {                                                    \
    DO_STEP(0, Q0.x); DO_STEP(1, Q0.y); DO_STEP(2, Q0.z); DO_STEP(3, Q0.w);   \
    DO_STEP(4, Q1.x); DO_STEP(5, Q1.y); DO_STEP(6, Q1.z); DO_STEP(7, Q1.w);   \
  } while (0)

  // prologue: every wave loads its local chunk 0
  PRE(a0, a1, 0);
  __syncthreads();

  for (int G = 0; G < NGC; ++G) {
    const int lc = G - LAGCH * w;
    if (lc >= 0 && lc < NLCB) {
      const int s0 = lc << 3;
      if ((lc & 1) == 0) {
        PRE(b0, b1, lc + 1);
        RINGLOAD;
        STEP8(a0, a1);
      } else {
        PRE(a0, a1, lc + 1);
        RINGLOAD;
        STEP8(b0, b1);
      }
      if (w < 7 && lane == 49) {
#pragma unroll
        for (int k = 0; k < 8; k++) {
          int j = s0 + k - 49;
          if ((unsigned)j < 800u) bnd[w][j & 127] = wrv[k];
        }
      }
      rcarry = rbv[7];
    }
    __syncthreads();
  }

  // res is pre-scaled; unscale (1/SCALE) and apply 0.001/16 in one constant.
  if (w == 7 && lane == 49) atomicAdd(&out[which], res * 4.3321699e-6f);

#undef PRE
#undef RINGLOAD
#undef DO_STEP
#undef STEP8
}

extern "C" void kernel_launch(void* const* d_in, const int* in_sizes, int n_in,
                              void* d_out, int out_size, void* d_ws, size_t ws_size,
                              hipStream_t stream) {
  const float* d         = (const float*)d_in[0];
  const int*   mel_len   = (const int*)d_in[1];
  const float* mel       = (const float*)d_in[2];
  const float* post      = (const float*)d_in[3];
  const float* target    = (const float*)d_in[4];
  const void*  src_mask  = d_in[5];
  const void*  pred_mask = d_in[6];
  float* out = (float*)d_out;

  int* flags = (int*)d_ws;
  __half* Dsk = (__half*)((char*)d_ws + 256);
  size_t per = (size_t)HALF_PER_SLOT * sizeof(__half);  // 1.31 MB per problem
  int slots = 0;
  if (ws_size > 256) slots = (int)((ws_size - 256) / per);
  if (slots > 32) slots = 32;

  (void)hipMemsetAsync(d_out, 0, 3 * sizeof(float), stream);
  detect_dloss_kernel<<<1, 256, 0, stream>>>(d, mel_len, src_mask, pred_mask, flags, out);
  if (slots < 1) return;

  for (int base = 0; base < 32; base += slots) {
    int g = (32 - base < slots) ? (32 - base) : slots;
    cost_kernel<<<dim3(13, 13, g), 256, 0, stream>>>(mel, post, target, pred_mask,
                                                     flags, Dsk, base);
    dtw_kernel<<<g, 512, 0, stream>>>(Dsk, out, base);
  }
}